// Round 6
// baseline (392.204 us; speedup 1.0000x reference)
//
#include <hip/hip_runtime.h>
#include <hip/hip_bf16.h>
#include <math.h>

#define HH 512
#define WW 512
#define BC 48
#define GW 544                    // padded width: 16 left + 512 + 16 right
#define GH 545                    // padded height: 16 top + 512 + 17 bottom
#define PST (GH * GW)             // plane stride in elements (296480)

// LDS staging geometry for k_corr_mfma (32-row chunks)
#define ROWB 384                  // staged bytes per row (192 bf16 cols)
#define COPYSTRIDE 12352          // 32*384 + 64 pad -> +16 bank shift between copies
#define BUFSTRIDE (2 * COPYSTRIDE)
#define LDSBYTES (2 * BUFSTRIDE)  // 49408

// prep tile LDS strides
#define SIMS 98                   // bf16 row stride for 96-col staged tile (+2 pad)

typedef __bf16 v8bf __attribute__((ext_vector_type(8)));
typedef float v16f __attribute__((ext_vector_type(16)));

// ---------------------------------------------------------------------------
// Template normalization: Tn = (t - mean)/||t - mean|| per (b,c), bf16 out.
// ---------------------------------------------------------------------------
__global__ __launch_bounds__(256) void k_template(const float* __restrict__ t,
                                                  __hip_bfloat16* __restrict__ tn)
{
    __shared__ float red[256];
    const int bc = blockIdx.x, tid = threadIdx.x;
    const float* tp = t + bc * 1024;
    float v0 = tp[tid], v1 = tp[tid + 256], v2 = tp[tid + 512], v3 = tp[tid + 768];
    red[tid] = v0 + v1 + v2 + v3;
    __syncthreads();
    for (int sft = 128; sft > 0; sft >>= 1) {
        if (tid < sft) red[tid] += red[tid + sft];
        __syncthreads();
    }
    float mean = red[0] * (1.0f / 1024.0f);
    __syncthreads();
    float c0 = v0 - mean, c1 = v1 - mean, c2 = v2 - mean, c3 = v3 - mean;
    red[tid] = c0 * c0 + c1 * c1 + c2 * c2 + c3 * c3;
    __syncthreads();
    for (int sft = 128; sft > 0; sft >>= 1) {
        if (tid < sft) red[tid] += red[tid + sft];
        __syncthreads();
    }
    float norm = sqrtf(red[0]);
    __hip_bfloat16* o = tn + bc * 1024;
    o[tid] = __float2bfloat16(c0 / norm);
    o[tid + 256] = __float2bfloat16(c1 / norm);
    o[tid + 512] = __float2bfloat16(c2 / norm);
    o[tid + 768] = __float2bfloat16(c3 / norm);
}

// ---------------------------------------------------------------------------
// K1: fused 32x32 local-mean centering. Tile 64 cols x 128 rows per block.
// Stage im (bf16) with full halo, hbox via running sums in LDS, vertical
// roll, write UN-normalized im_c as single padded bf16 plane T0 (in d_out).
// ---------------------------------------------------------------------------
__global__ __launch_bounds__(256) void k_center2(const float* __restrict__ im,
                                                 __hip_bfloat16* __restrict__ T0)
{
    __shared__ __hip_bfloat16 sim[159 * SIMS];   // rows i0-15..i0+143, cols j0-16..j0+79
    __shared__ float hs[159 * 64];               // hbox sums
    const int j0 = blockIdx.x * 64;
    const int i0 = blockIdx.y * 128;
    const int plane = blockIdx.z;
    const int tid = threadIdx.x;
    const size_t iplane = (size_t)plane * HH * WW;
    const size_t gplane = (size_t)plane * PST;

    for (int k = tid; k < 159 * 96; k += 256) {
        int r = k / 96, c = k - r * 96;
        int gi = i0 + r - 15, gj = j0 + c - 16;
        float v = (gi >= 0 && gi < HH && gj >= 0 && gj < WW)
                      ? im[iplane + (size_t)gi * WW + gj] : 0.f;
        sim[r * SIMS + c] = __float2bfloat16(v);
    }
    __syncthreads();

    if (tid < 159) {
        const __hip_bfloat16* sr = sim + tid * SIMS;
        float s0 = 0.f;
#pragma unroll
        for (int c = 1; c <= 32; c++) s0 += __bfloat162float(sr[c]);
        hs[tid * 64] = s0;
        for (int j = 1; j < 64; j++) {
            s0 += __bfloat162float(sr[j + 32]) - __bfloat162float(sr[j]);
            hs[tid * 64 + j] = s0;
        }
    }
    __syncthreads();

    const int tc = tid & 63;
    const int lr0 = (tid >> 6) * 32;
    float run = 0.f;
#pragma unroll
    for (int d = 0; d < 32; d++) run += hs[(lr0 + d) * 64 + tc];
    for (int rr = 0; rr < 32; rr++) {
        int lr = lr0 + rr;
        int gi = i0 + lr;
        float imv = __bfloat162float(sim[(lr + 15) * SIMS + tc + 16]);
        float val = imv - run * (1.0f / 1024.0f);
        T0[gplane + (size_t)(16 + gi) * GW + 16 + j0 + tc] = __float2bfloat16(val);
        if (rr < 31) run += hs[(lr + 32) * 64 + tc] - hs[lr * 64 + tc];
    }
    // ---- pad zeroing for T0 ----
    if (blockIdx.x == 0) {
        for (int k = tid; k < 128 * 16; k += 256) {
            int rr = k >> 4, x = k & 15;
            T0[gplane + (size_t)(16 + i0 + rr) * GW + x] = __float2bfloat16(0.f);
        }
    }
    if (blockIdx.x == 7) {
        for (int k = tid; k < 128 * 16; k += 256) {
            int rr = k >> 4, x = k & 15;
            T0[gplane + (size_t)(16 + i0 + rr) * GW + 528 + x] = __float2bfloat16(0.f);
        }
    }
    if (blockIdx.x == 0 && blockIdx.y == 0) {
        for (int k = tid; k < 16 * GW; k += 256)
            T0[gplane + k] = __float2bfloat16(0.f);
    }
    if (blockIdx.x == 0 && blockIdx.y == 3) {
        size_t b = gplane + (size_t)528 * GW;
        for (int k = tid; k < 17 * GW; k += 256)
            T0[b + k] = __float2bfloat16(0.f);
    }
}

// ---------------------------------------------------------------------------
// K2: fused energy normalization. Stage T0 tile (halo safe: T0 read-only),
// hbox of squares via running sums, vertical roll -> energy, write normalized
// dual parity copies G0/G1 (+ all their pads).
// ---------------------------------------------------------------------------
__global__ __launch_bounds__(256) void k_norm2(const __hip_bfloat16* __restrict__ T0,
                                               __hip_bfloat16* __restrict__ G0,
                                               __hip_bfloat16* __restrict__ G1)
{
    __shared__ __hip_bfloat16 sim[159 * SIMS];
    __shared__ float hs[159 * 64];
    const int j0 = blockIdx.x * 64;
    const int i0 = blockIdx.y * 128;
    const int plane = blockIdx.z;
    const int tid = threadIdx.x;
    const size_t gplane = (size_t)plane * PST;

    // phys rows i0+1 .. i0+159, phys cols j0 .. j0+95 — always in array bounds
    for (int k = tid; k < 159 * 96; k += 256) {
        int r = k / 96, c = k - r * 96;
        sim[r * SIMS + c] = T0[gplane + (size_t)(i0 + 1 + r) * GW + j0 + c];
    }
    __syncthreads();

    if (tid < 159) {
        const __hip_bfloat16* sr = sim + tid * SIMS;
        float s0 = 0.f;
#pragma unroll
        for (int c = 1; c <= 32; c++) {
            float v = __bfloat162float(sr[c]);
            s0 += v * v;
        }
        hs[tid * 64] = s0;
        for (int j = 1; j < 64; j++) {
            float a = __bfloat162float(sr[j + 32]);
            float b = __bfloat162float(sr[j]);
            s0 += a * a - b * b;
            hs[tid * 64 + j] = s0;
        }
    }
    __syncthreads();

    const int tc = tid & 63;
    const int lr0 = (tid >> 6) * 32;
    float run = 0.f;
#pragma unroll
    for (int d = 0; d < 32; d++) run += hs[(lr0 + d) * 64 + tc];
    for (int rr = 0; rr < 32; rr++) {
        int lr = lr0 + rr;
        int gi = i0 + lr;
        int c = j0 + tc;
        float e = sqrtf(fmaxf(run, 0.f));
        float v = __bfloat162float(sim[(lr + 15) * SIMS + tc + 16]) / e;
        __hip_bfloat16 w = __float2bfloat16(v);
        size_t pr = gplane + (size_t)(16 + gi) * GW;
        G0[pr + 16 + c] = w;
        G1[pr + 15 + c] = w;
        if (rr < 31) run += hs[(lr + 32) * 64 + tc] - hs[lr * 64 + tc];
    }
    // ---- pad zeroing for G0/G1 ----
    if (blockIdx.x == 0) {
        for (int k = tid; k < 128 * 16; k += 256) {
            int rr = k >> 4, x = k & 15;
            size_t pr = gplane + (size_t)(16 + i0 + rr) * GW;
            G0[pr + x] = __float2bfloat16(0.f);
            if (x < 15) G1[pr + x] = __float2bfloat16(0.f);
        }
    }
    if (blockIdx.x == 7) {
        for (int k = tid; k < 128 * 17; k += 256) {
            int rr = k / 17, x = k % 17;
            size_t pr = gplane + (size_t)(16 + i0 + rr) * GW;
            G1[pr + 527 + x] = __float2bfloat16(0.f);
            if (x > 0) G0[pr + 527 + x] = __float2bfloat16(0.f);
        }
    }
    if (blockIdx.x == 0 && blockIdx.y == 0) {
        for (int k = tid; k < 16 * GW; k += 256) {
            G0[gplane + k] = __float2bfloat16(0.f);
            G1[gplane + k] = __float2bfloat16(0.f);
        }
    }
    if (blockIdx.x == 0 && blockIdx.y == 3) {
        size_t b = gplane + (size_t)528 * GW;
        for (int k = tid; k < 17 * GW; k += 256) {
            G0[b + k] = __float2bfloat16(0.f);
            G1[b + k] = __float2bfloat16(0.f);
        }
    }
}

// ---------------------------------------------------------------------------
// Compute 32 sweep iterations (one chunk) from LDS buffer at dword base.
// Ring slot arithmetic identical to the round-2-validated version.
// ---------------------------------------------------------------------------
__device__ __forceinline__ void compute_chunk(const unsigned int* __restrict__ p0,
                                              v8bf a0, v8bf a1,
                                              float (&ring)[32],
                                              int h, int Tbase, int i0,
                                              float* outp)
{
    const v16f Z = 0.0f;
#pragma unroll
    for (int t = 0; t < 32; ++t) {
        const unsigned int* p = p0 + t * (ROWB / 4);
        union { unsigned int u[4]; v8bf v; } B0, B1;
        B0.u[0] = p[0];  B0.u[1] = p[1];  B0.u[2] = p[2];  B0.u[3] = p[3];
        B1.u[0] = p[8];  B1.u[1] = p[9];  B1.u[2] = p[10]; B1.u[3] = p[11];
        v16f P = __builtin_amdgcn_mfma_f32_32x32x16_bf16(a0, B0.v, Z, 0, 0, 0);
        P = __builtin_amdgcn_mfma_f32_32x32x16_bf16(a1, B1.v, P, 0, 0, 0);
#pragma unroll
        for (int q = 0; q < 16; ++q) {
            const int baseq = (q & 3) + 8 * (q >> 2);
            ring[(t - baseq) & 31] += P[q];
        }
        const int T = Tbase + t;                 // wave-uniform
        float va = ring[(t + 1) & 31];
        float vb = ring[(t + 5) & 31];
        if (T >= 31 && T <= 94) {                // uniform: skip dead retires
            float val = h ? vb : va;
            val += __shfl_xor(val, 32);
            const int ret = i0 - 31 + T;
            if (h == 0) outp[(size_t)ret * WW] = val;
        }
        ring[(t + 1) & 31] = h ? va : 0.f;       // zeroing must stay unconditional
        ring[(t + 5) & 31] = h ? 0.f : vb;
    }
}

// ---------------------------------------------------------------------------
// Correlation: MFMA scatter + async LDS double buffer, 32-row chunks
// (3 barriers per block instead of 6). Block: 4 waves, 128 cols x 64 rows.
// Staging split across waves: 24 x 1KB segments per chunk, 6 per wave.
// ---------------------------------------------------------------------------
__global__ __launch_bounds__(256) void k_corr_mfma(const __hip_bfloat16* __restrict__ G0,
                                                   const __hip_bfloat16* __restrict__ G1,
                                                   const __hip_bfloat16* __restrict__ Tn,
                                                   float* __restrict__ out)
{
    __shared__ __align__(16) char lds[LDSBYTES];
    const int tid = threadIdx.x;
    const int wid = tid >> 6;
    const int lane = tid & 63;
    const int n = lane & 31;
    const int h = lane >> 5;
    const int j0 = blockIdx.x * 128;
    const int j0w = j0 + wid * 32;
    const int i0 = blockIdx.y * 64;
    const int plane = blockIdx.z;

    // A-operand: Tn fragments (whole template in registers)
    const v8bf* tp = (const v8bf*)(Tn + (size_t)plane * 1024 + n * 32 + 8 * h);
    const v8bf a0 = tp[0];
    const v8bf a1 = tp[2];

    // Reader: parity copy + dword base within staged row
    const int c0 = j0w + n - 15 + 8 * h;
    const int sel = c0 & 1;
    const int dbase = (32 * wid + n + 1 + 8 * h - sel) >> 1;
    const unsigned int* Lr = (const unsigned int*)(lds + sel * COPYSTRIDE) + dbase;

    const __hip_bfloat16* g0p = G0 + (size_t)plane * PST + (size_t)(i0 + 1) * GW + j0;
    const __hip_bfloat16* g1p = G1 + (size_t)plane * PST + (size_t)(i0 + 1) * GW + j0;

    // Stager: this wave's 6 of 24 segments (s = wid + 4k)
    const __hip_bfloat16* srcp[6];
    int ldso[6];
#pragma unroll
    for (int k = 0; k < 6; ++k) {
        int s = wid + 4 * k;
        int cp = (s >= 12) ? 1 : 0;
        int c2 = cp ? (s - 12) : s;
        int q = c2 * 1024 + lane * 16;
        int rl = q / ROWB;
        int cb = q - rl * ROWB;
        srcp[k] = (cp ? g1p : g0p) + rl * GW + (cb >> 1);
        ldso[k] = cp * COPYSTRIDE + c2 * 1024;
    }

    float ring[32];
#pragma unroll
    for (int s = 0; s < 32; s++) ring[s] = 0.f;

    float* outp = out + (size_t)plane * HH * WW + j0w + n;

    auto stage = [&](int R, int b) {
#pragma unroll
        for (int k = 0; k < 6; ++k) {
            __builtin_amdgcn_global_load_lds(
                (const __attribute__((address_space(1))) void*)(srcp[k] + (size_t)R * GW),
                (__attribute__((address_space(3))) void*)(lds + b * BUFSTRIDE + ldso[k]),
                16, 0, 0);
        }
    };

    stage(0, 0);
    stage(32, 1);
    __syncthreads();

    compute_chunk(Lr, a0, a1, ring, h, 0, i0, outp);
    __syncthreads();
    stage(64, 0);
    compute_chunk(Lr + BUFSTRIDE / 4, a0, a1, ring, h, 32, i0, outp);
    __syncthreads();
    compute_chunk(Lr, a0, a1, ring, h, 64, i0, outp);
}

// ---------------------------------------------------------------------------
// Orchestration.
//   d_out : T0 (un-normalized padded bf16 im_c, 28.5 MB) -> final output
//   d_ws  : G0, G1 (bf16 padded dual copies), Tn (bf16)  — ~57 MB
// ---------------------------------------------------------------------------
extern "C" void kernel_launch(void* const* d_in, const int* in_sizes, int n_in,
                              void* d_out, int out_size, void* d_ws, size_t ws_size,
                              hipStream_t stream)
{
    const float* im = (const float*)d_in[0];
    const float* tmpl = (const float*)d_in[1];
    float* outp = (float*)d_out;
    __hip_bfloat16* T0 = (__hip_bfloat16*)d_out;
    __hip_bfloat16* G0 = (__hip_bfloat16*)d_ws;
    __hip_bfloat16* G1 = G0 + (size_t)BC * PST;
    __hip_bfloat16* Tn = G1 + (size_t)BC * PST;

    k_template<<<48, 256, 0, stream>>>(tmpl, Tn);
    k_center2<<<dim3(8, 4, BC), 256, 0, stream>>>(im, T0);
    k_norm2<<<dim3(8, 4, BC), 256, 0, stream>>>(T0, G0, G1);
    k_corr_mfma<<<dim3(4, 8, BC), 256, 0, stream>>>(G0, G1, Tn, outp);
}

// Round 7
// 299.556 us; speedup vs baseline: 1.3093x; 1.3093x over previous
//
#include <hip/hip_runtime.h>
#include <hip/hip_bf16.h>
#include <math.h>

#define HH 512
#define WW 512
#define BC 48
#define GW 544                    // padded width: 16 left + 512 + 16 right
#define GH 545                    // padded height: 16 top + 512 + 17 bottom
#define PST (GH * GW)             // plane stride in elements (296480)

// LDS staging geometry for k_corr_mfma (16-row chunks — round-5 validated)
#define ROWB 384                  // staged bytes per row (192 bf16 cols)
#define COPYSTRIDE 6208           // bytes between parity copies (16B aligned, bank-shifted)
#define BUFSTRIDE (2 * COPYSTRIDE)
#define LDSBYTES (2 * BUFSTRIDE)  // 24832

// prep tile LDS strides
#define SIMS 98                   // bf16 row stride for 96-col staged tile (+2 pad)

typedef __bf16 v8bf __attribute__((ext_vector_type(8)));
typedef float v16f __attribute__((ext_vector_type(16)));

// ---------------------------------------------------------------------------
// Template normalization: Tn = (t - mean)/||t - mean|| per (b,c), bf16 out.
// ---------------------------------------------------------------------------
__global__ __launch_bounds__(256) void k_template(const float* __restrict__ t,
                                                  __hip_bfloat16* __restrict__ tn)
{
    __shared__ float red[256];
    const int bc = blockIdx.x, tid = threadIdx.x;
    const float* tp = t + bc * 1024;
    float v0 = tp[tid], v1 = tp[tid + 256], v2 = tp[tid + 512], v3 = tp[tid + 768];
    red[tid] = v0 + v1 + v2 + v3;
    __syncthreads();
    for (int sft = 128; sft > 0; sft >>= 1) {
        if (tid < sft) red[tid] += red[tid + sft];
        __syncthreads();
    }
    float mean = red[0] * (1.0f / 1024.0f);
    __syncthreads();
    float c0 = v0 - mean, c1 = v1 - mean, c2 = v2 - mean, c3 = v3 - mean;
    red[tid] = c0 * c0 + c1 * c1 + c2 * c2 + c3 * c3;
    __syncthreads();
    for (int sft = 128; sft > 0; sft >>= 1) {
        if (tid < sft) red[tid] += red[tid + sft];
        __syncthreads();
    }
    float norm = sqrtf(red[0]);
    __hip_bfloat16* o = tn + bc * 1024;
    o[tid] = __float2bfloat16(c0 / norm);
    o[tid + 256] = __float2bfloat16(c1 / norm);
    o[tid + 512] = __float2bfloat16(c2 / norm);
    o[tid + 768] = __float2bfloat16(c3 / norm);
}

// ---------------------------------------------------------------------------
// K1: fused 32x32 local-mean centering (round-6, unchanged this round).
// ---------------------------------------------------------------------------
__global__ __launch_bounds__(256) void k_center2(const float* __restrict__ im,
                                                 __hip_bfloat16* __restrict__ T0)
{
    __shared__ __hip_bfloat16 sim[159 * SIMS];
    __shared__ float hs[159 * 64];
    const int j0 = blockIdx.x * 64;
    const int i0 = blockIdx.y * 128;
    const int plane = blockIdx.z;
    const int tid = threadIdx.x;
    const size_t iplane = (size_t)plane * HH * WW;
    const size_t gplane = (size_t)plane * PST;

    for (int k = tid; k < 159 * 96; k += 256) {
        int r = k / 96, c = k - r * 96;
        int gi = i0 + r - 15, gj = j0 + c - 16;
        float v = (gi >= 0 && gi < HH && gj >= 0 && gj < WW)
                      ? im[iplane + (size_t)gi * WW + gj] : 0.f;
        sim[r * SIMS + c] = __float2bfloat16(v);
    }
    __syncthreads();

    if (tid < 159) {
        const __hip_bfloat16* sr = sim + tid * SIMS;
        float s0 = 0.f;
#pragma unroll
        for (int c = 1; c <= 32; c++) s0 += __bfloat162float(sr[c]);
        hs[tid * 64] = s0;
        for (int j = 1; j < 64; j++) {
            s0 += __bfloat162float(sr[j + 32]) - __bfloat162float(sr[j]);
            hs[tid * 64 + j] = s0;
        }
    }
    __syncthreads();

    const int tc = tid & 63;
    const int lr0 = (tid >> 6) * 32;
    float run = 0.f;
#pragma unroll
    for (int d = 0; d < 32; d++) run += hs[(lr0 + d) * 64 + tc];
    for (int rr = 0; rr < 32; rr++) {
        int lr = lr0 + rr;
        int gi = i0 + lr;
        float imv = __bfloat162float(sim[(lr + 15) * SIMS + tc + 16]);
        float val = imv - run * (1.0f / 1024.0f);
        T0[gplane + (size_t)(16 + gi) * GW + 16 + j0 + tc] = __float2bfloat16(val);
        if (rr < 31) run += hs[(lr + 32) * 64 + tc] - hs[lr * 64 + tc];
    }
    if (blockIdx.x == 0) {
        for (int k = tid; k < 128 * 16; k += 256) {
            int rr = k >> 4, x = k & 15;
            T0[gplane + (size_t)(16 + i0 + rr) * GW + x] = __float2bfloat16(0.f);
        }
    }
    if (blockIdx.x == 7) {
        for (int k = tid; k < 128 * 16; k += 256) {
            int rr = k >> 4, x = k & 15;
            T0[gplane + (size_t)(16 + i0 + rr) * GW + 528 + x] = __float2bfloat16(0.f);
        }
    }
    if (blockIdx.x == 0 && blockIdx.y == 0) {
        for (int k = tid; k < 16 * GW; k += 256)
            T0[gplane + k] = __float2bfloat16(0.f);
    }
    if (blockIdx.x == 0 && blockIdx.y == 3) {
        size_t b = gplane + (size_t)528 * GW;
        for (int k = tid; k < 17 * GW; k += 256)
            T0[b + k] = __float2bfloat16(0.f);
    }
}

// ---------------------------------------------------------------------------
// K2: fused energy normalization (round-6, unchanged this round).
// ---------------------------------------------------------------------------
__global__ __launch_bounds__(256) void k_norm2(const __hip_bfloat16* __restrict__ T0,
                                               __hip_bfloat16* __restrict__ G0,
                                               __hip_bfloat16* __restrict__ G1)
{
    __shared__ __hip_bfloat16 sim[159 * SIMS];
    __shared__ float hs[159 * 64];
    const int j0 = blockIdx.x * 64;
    const int i0 = blockIdx.y * 128;
    const int plane = blockIdx.z;
    const int tid = threadIdx.x;
    const size_t gplane = (size_t)plane * PST;

    for (int k = tid; k < 159 * 96; k += 256) {
        int r = k / 96, c = k - r * 96;
        sim[r * SIMS + c] = T0[gplane + (size_t)(i0 + 1 + r) * GW + j0 + c];
    }
    __syncthreads();

    if (tid < 159) {
        const __hip_bfloat16* sr = sim + tid * SIMS;
        float s0 = 0.f;
#pragma unroll
        for (int c = 1; c <= 32; c++) {
            float v = __bfloat162float(sr[c]);
            s0 += v * v;
        }
        hs[tid * 64] = s0;
        for (int j = 1; j < 64; j++) {
            float a = __bfloat162float(sr[j + 32]);
            float b = __bfloat162float(sr[j]);
            s0 += a * a - b * b;
            hs[tid * 64 + j] = s0;
        }
    }
    __syncthreads();

    const int tc = tid & 63;
    const int lr0 = (tid >> 6) * 32;
    float run = 0.f;
#pragma unroll
    for (int d = 0; d < 32; d++) run += hs[(lr0 + d) * 64 + tc];
    for (int rr = 0; rr < 32; rr++) {
        int lr = lr0 + rr;
        int gi = i0 + lr;
        int c = j0 + tc;
        float e = sqrtf(fmaxf(run, 0.f));
        float v = __bfloat162float(sim[(lr + 15) * SIMS + tc + 16]) / e;
        __hip_bfloat16 w = __float2bfloat16(v);
        size_t pr = gplane + (size_t)(16 + gi) * GW;
        G0[pr + 16 + c] = w;
        G1[pr + 15 + c] = w;
        if (rr < 31) run += hs[(lr + 32) * 64 + tc] - hs[lr * 64 + tc];
    }
    if (blockIdx.x == 0) {
        for (int k = tid; k < 128 * 16; k += 256) {
            int rr = k >> 4, x = k & 15;
            size_t pr = gplane + (size_t)(16 + i0 + rr) * GW;
            G0[pr + x] = __float2bfloat16(0.f);
            if (x < 15) G1[pr + x] = __float2bfloat16(0.f);
        }
    }
    if (blockIdx.x == 7) {
        for (int k = tid; k < 128 * 17; k += 256) {
            int rr = k / 17, x = k % 17;
            size_t pr = gplane + (size_t)(16 + i0 + rr) * GW;
            G1[pr + 527 + x] = __float2bfloat16(0.f);
            if (x > 0) G0[pr + 527 + x] = __float2bfloat16(0.f);
        }
    }
    if (blockIdx.x == 0 && blockIdx.y == 0) {
        for (int k = tid; k < 16 * GW; k += 256) {
            G0[gplane + k] = __float2bfloat16(0.f);
            G1[gplane + k] = __float2bfloat16(0.f);
        }
    }
    if (blockIdx.x == 0 && blockIdx.y == 3) {
        size_t b = gplane + (size_t)528 * GW;
        for (int k = tid; k < 17 * GW; k += 256) {
            G0[b + k] = __float2bfloat16(0.f);
            G1[b + k] = __float2bfloat16(0.f);
        }
    }
}

// ---------------------------------------------------------------------------
// Corr compute: rotating-accumulator scheme. C slot base b=(q&3)+8*(q>>2)+4h
// holds (at step start) out row i = r+15-b. MFMA C-chaining does the
// accumulate; after MFMA, slot b=31 (h1 lanes, q15) retires a complete row;
// rotation b->b+1: within-lane renames + 4 half-crossing shfl_xor + inject 0.
// Crossings: b3(h0,q3)->b4(h1,q0), b7(h1,q3)->b8(h0,q4), b11(h0,q7)->b12(h1,q4),
// b15(h1,q7)->b16(h0,q8), b19(h0,q11)->b20(h1,q8), b23(h1,q11)->b24(h0,q12),
// b27(h0,q15)->b28(h1,q12), b31(h1,q15)->retire; inject 0 at b0(h0,q0).
// ---------------------------------------------------------------------------
template <int PHASE>
__device__ __forceinline__ void compute_chunk(const unsigned int* __restrict__ Lr,
                                              v8bf a0, v8bf a1,
                                              float (&C)[16],
                                              int h, int Tbase, int i0,
                                              float* outp)
{
#pragma unroll
    for (int t = 0; t < 16; ++t) {
        const unsigned int* p = Lr + PHASE * (BUFSTRIDE / 4) + t * (ROWB / 4);
        union { unsigned int u[4]; v8bf v; } B0, B1;
        B0.u[0] = p[0];  B0.u[1] = p[1];  B0.u[2] = p[2];  B0.u[3] = p[3];
        B1.u[0] = p[8];  B1.u[1] = p[9];  B1.u[2] = p[10]; B1.u[3] = p[11];
        v16f c;
#pragma unroll
        for (int q = 0; q < 16; ++q) c[q] = C[q];
        c = __builtin_amdgcn_mfma_f32_32x32x16_bf16(a1, B1.v, c, 0, 0, 0);
        c = __builtin_amdgcn_mfma_f32_32x32x16_bf16(a0, B0.v, c, 0, 0, 0);
        const int T = Tbase + t;                 // wave-uniform
        if (T >= 31 && T <= 94) {                // live retires only
            if (h) {
                const int ret = i0 - 31 + T;
                outp[(size_t)ret * WW] = c[15];  // b31 = complete out row
            }
        }
        // rotate b -> b+1
        float t3  = __shfl_xor(c[3], 32);
        float t7  = __shfl_xor(c[7], 32);
        float t11 = __shfl_xor(c[11], 32);
        float t15 = __shfl_xor(c[15], 32);
        C[0]  = h ? t3  : 0.f;                   // b4 <- b3 | inject 0 at b0
        C[4]  = h ? t7  : t3;                    // b12<-b11 | b8 <- b7
        C[8]  = h ? t11 : t7;                    // b20<-b19 | b16<- b15
        C[12] = h ? t15 : t11;                   // b28<-b27 | b24<- b23
#pragma unroll
        for (int g = 0; g < 4; ++g)
#pragma unroll
            for (int k = 1; k < 4; ++k)
                C[4 * g + k] = c[4 * g + k - 1]; // within-lane renames
    }
}

// ---------------------------------------------------------------------------
// Correlation: MFMA rotating-accumulator + async LDS double buffer
// (round-5 validated staging: 16-row chunks, wave-split 12x1KB segments).
// Block: 4 waves, 128 output cols x 64 output rows, sweep 96 image rows.
// ---------------------------------------------------------------------------
__global__ __launch_bounds__(256) void k_corr_mfma(const __hip_bfloat16* __restrict__ G0,
                                                   const __hip_bfloat16* __restrict__ G1,
                                                   const __hip_bfloat16* __restrict__ Tn,
                                                   float* __restrict__ out)
{
    __shared__ __align__(16) char lds[LDSBYTES];
    const int tid = threadIdx.x;
    const int wid = tid >> 6;
    const int lane = tid & 63;
    const int n = lane & 31;
    const int h = lane >> 5;
    const int j0 = blockIdx.x * 128;
    const int j0w = j0 + wid * 32;
    const int i0 = blockIdx.y * 64;
    const int plane = blockIdx.z;

    // A-operand: Tn fragments (whole template in registers)
    const v8bf* tp = (const v8bf*)(Tn + (size_t)plane * 1024 + n * 32 + 8 * h);
    const v8bf a0 = tp[0];
    const v8bf a1 = tp[2];

    // Reader: parity copy + dword base within staged row
    const int c0 = j0w + n - 15 + 8 * h;
    const int sel = c0 & 1;
    const int dbase = (32 * wid + n + 1 + 8 * h - sel) >> 1;
    const unsigned int* Lr = (const unsigned int*)(lds + sel * COPYSTRIDE) + dbase;

    const __hip_bfloat16* g0p = G0 + (size_t)plane * PST + (size_t)(i0 + 1) * GW + j0;
    const __hip_bfloat16* g1p = G1 + (size_t)plane * PST + (size_t)(i0 + 1) * GW + j0;

    // Stager: this wave's 3 of the 12 segments (s = wid, wid+4, wid+8)
    const __hip_bfloat16* srcp[3];
    int ldso[3];
#pragma unroll
    for (int k = 0; k < 3; ++k) {
        int s = wid + 4 * k;
        int cp = (s >= 6) ? 1 : 0;
        int c2 = cp ? (s - 6) : s;
        int q = c2 * 1024 + lane * 16;
        int rl = q / ROWB;
        int cb = q - rl * ROWB;
        srcp[k] = (cp ? g1p : g0p) + rl * GW + (cb >> 1);
        ldso[k] = cp * COPYSTRIDE + c2 * 1024;
    }

    float C[16];
#pragma unroll
    for (int s = 0; s < 16; s++) C[s] = 0.f;

    float* outp = out + (size_t)plane * HH * WW + j0w + n;

    auto stage = [&](int R, int b) {
#pragma unroll
        for (int k = 0; k < 3; ++k) {
            __builtin_amdgcn_global_load_lds(
                (const __attribute__((address_space(1))) void*)(srcp[k] + (size_t)R * GW),
                (__attribute__((address_space(3))) void*)(lds + b * BUFSTRIDE + ldso[k]),
                16, 0, 0);
        }
    };

    stage(0, 0);
    stage(16, 1);
    __syncthreads();

    for (int k2 = 0; k2 < 3; ++k2) {
        compute_chunk<0>(Lr, a0, a1, C, h, 32 * k2, i0, outp);
        __syncthreads();
        if (k2 < 2) stage(32 * k2 + 32, 0);
        compute_chunk<1>(Lr, a0, a1, C, h, 32 * k2 + 16, i0, outp);
        __syncthreads();
        if (k2 < 2) stage(32 * k2 + 48, 1);
    }
}

// ---------------------------------------------------------------------------
// Orchestration.
//   d_out : T0 (un-normalized padded bf16 im_c) -> final output
//   d_ws  : G0, G1 (bf16 padded dual copies), Tn (bf16)  — ~57 MB
// ---------------------------------------------------------------------------
extern "C" void kernel_launch(void* const* d_in, const int* in_sizes, int n_in,
                              void* d_out, int out_size, void* d_ws, size_t ws_size,
                              hipStream_t stream)
{
    const float* im = (const float*)d_in[0];
    const float* tmpl = (const float*)d_in[1];
    float* outp = (float*)d_out;
    __hip_bfloat16* T0 = (__hip_bfloat16*)d_out;
    __hip_bfloat16* G0 = (__hip_bfloat16*)d_ws;
    __hip_bfloat16* G1 = G0 + (size_t)BC * PST;
    __hip_bfloat16* Tn = G1 + (size_t)BC * PST;

    k_template<<<48, 256, 0, stream>>>(tmpl, Tn);
    k_center2<<<dim3(8, 4, BC), 256, 0, stream>>>(im, T0);
    k_norm2<<<dim3(8, 4, BC), 256, 0, stream>>>(T0, G0, G1);
    k_corr_mfma<<<dim3(4, 8, BC), 256, 0, stream>>>(G0, G1, Tn, outp);
}